// Round 1
// baseline (640.334 us; speedup 1.0000x reference)
//
#include <hip/hip_runtime.h>
#include <hip/hip_bf16.h>

typedef __attribute__((ext_vector_type(8))) short bf16x8_t;
typedef __attribute__((ext_vector_type(4))) float f32x4_t;

__device__ inline unsigned short f2bf(float x) {
    union { float f; unsigned int u; } v; v.f = x;
    unsigned int r = v.u + 0x7FFFu + ((v.u >> 16) & 1u);
    return (unsigned short)(r >> 16);
}

// MODE 0: overlap part. M=2304 rows/cols per batch (batch = v in 0..7).
//   A row n -> z1[(b*8+v)*576 + h*24 + 12 + j], n=(b*24+h)*12+j
//   B row m -> z2[(b*8+(v+1)%8)*576 + h*24 + j]
// MODE 1: tile part. M=576 per batch (batch = bv in 0..63).
//   A row s -> z1[bv*576+s], B row t -> z2[bv*576+t]
template <int MODE>
__global__ __launch_bounds__(256) void fused_gemm_lse(
    const float* __restrict__ z1, const float* __restrict__ z2,
    float* __restrict__ rowsum, float* __restrict__ colsum,
    float* __restrict__ diag) {
    constexpr int M = (MODE == 0) ? 2304 : 576;
    constexpr float inv_tau = (MODE == 0) ? (1.0f / 0.07f) : (1.0f / 0.2f);

    const int tid  = threadIdx.x;
    const int lane = tid & 63;
    const int w    = tid >> 6;
    const int wM   = w >> 1;      // 0..1
    const int wN   = w & 1;       // 0..1
    const int lr   = lane & 15;
    const int lg   = lane >> 4;
    const int brow = blockIdx.y, bcol = blockIdx.x, batch = blockIdx.z;

    __shared__ unsigned short lA[128][72];   // +8 halves pad: 16B, breaks bank conflicts
    __shared__ unsigned short lB[128][72];
    __shared__ int offA[128];
    __shared__ int offB[128];

    // precompute per-row global element offsets (-1 = out of range -> zeros)
    if (tid < 128) {
        int r = brow * 128 + tid;
        int off;
        if (MODE == 0) {
            int b = r / 288, rem = r % 288;
            int h = rem / 12, j = rem % 12;
            off = ((b * 8 + batch) * 576 + h * 24 + 12 + j) * 768;
        } else {
            off = (r < M) ? (batch * 576 + r) * 768 : -1;
        }
        offA[tid] = off;
    } else {
        int c = bcol * 128 + (tid - 128);
        int off;
        if (MODE == 0) {
            int b = c / 288, rem = c % 288;
            int h = rem / 12, j = rem % 12;
            off = ((b * 8 + ((batch + 1) & 7)) * 576 + h * 24 + j) * 768;
        } else {
            off = (c < M) ? (batch * 576 + c) * 768 : -1;
        }
        offB[tid - 128] = off;
    }
    __syncthreads();

    f32x4_t acc[4][4];
#pragma unroll
    for (int i = 0; i < 4; ++i)
#pragma unroll
        for (int j = 0; j < 4; ++j) acc[i][j] = (f32x4_t){0.f, 0.f, 0.f, 0.f};

    for (int kt = 0; kt < 12; ++kt) {
        const int k0 = kt * 64;
        // stage 128x64 of A and B as bf16 (convert in flight)
#pragma unroll
        for (int rr = 0; rr < 8; ++rr) {
            int f   = tid + (rr << 8);   // 0..2047 float4 slots
            int row = f >> 4;
            int c4  = f & 15;
            int oA = offA[row], oB = offB[row];
            float4 va = make_float4(0.f, 0.f, 0.f, 0.f);
            float4 vb = make_float4(0.f, 0.f, 0.f, 0.f);
            if (oA >= 0) va = *(const float4*)(z1 + oA + k0 + (c4 << 2));
            if (oB >= 0) vb = *(const float4*)(z2 + oB + k0 + (c4 << 2));
            ushort4 sa, sb;
            sa.x = f2bf(va.x); sa.y = f2bf(va.y); sa.z = f2bf(va.z); sa.w = f2bf(va.w);
            sb.x = f2bf(vb.x); sb.y = f2bf(vb.y); sb.z = f2bf(vb.z); sb.w = f2bf(vb.w);
            *(ushort4*)&lA[row][c4 << 2] = sa;
            *(ushort4*)&lB[row][c4 << 2] = sb;
        }
        __syncthreads();
#pragma unroll
        for (int kk = 0; kk < 64; kk += 32) {
            bf16x8_t av[4], bv[4];
#pragma unroll
            for (int i = 0; i < 4; ++i) {
                av[i] = *(const bf16x8_t*)&lA[wM * 64 + i * 16 + lr][kk + lg * 8];
                bv[i] = *(const bf16x8_t*)&lB[wN * 64 + i * 16 + lr][kk + lg * 8];
            }
#pragma unroll
            for (int i = 0; i < 4; ++i)
#pragma unroll
                for (int j = 0; j < 4; ++j)
                    acc[i][j] = __builtin_amdgcn_mfma_f32_16x16x32_bf16(
                        av[i], bv[j], acc[i][j], 0, 0, 0);
        }
        __syncthreads();
    }

    // Epilogue: logits L = acc*inv_tau; accumulate exp row/col sums; store diag.
    const int rowbase = brow * 128 + wM * 64;
    const int colbase = bcol * 128 + wN * 64;
    float colacc[4] = {0.f, 0.f, 0.f, 0.f};
#pragma unroll
    for (int i = 0; i < 4; ++i) {
#pragma unroll
        for (int reg = 0; reg < 4; ++reg) {
            int row = rowbase + i * 16 + lg * 4 + reg;
            bool rv = row < M;
            float rp = 0.f;
#pragma unroll
            for (int j = 0; j < 4; ++j) {
                int col = colbase + j * 16 + lr;
                float L = acc[i][j][reg] * inv_tau;
                float e = (rv && (col < M)) ? __expf(L) : 0.f;
                rp += e;
                colacc[j] += e;
                if (rv && row == col) diag[batch * M + row] = L;
            }
#pragma unroll
            for (int s = 1; s < 16; s <<= 1) rp += __shfl_xor(rp, s);
            if (lr == 0 && rv) atomicAdd(&rowsum[batch * M + row], rp);
        }
    }
#pragma unroll
    for (int j = 0; j < 4; ++j) {
        float c = colacc[j];
        c += __shfl_xor(c, 16);
        c += __shfl_xor(c, 32);
        int col = colbase + j * 16 + lr;
        if (lg == 0 && col < M) atomicAdd(&colsum[batch * M + col], c);
    }
}

// ws float layout:
// [0)        rs_ov 18432 | [18432) cs_ov 18432 | [36864) dg_ov 18432
// [55296)    rs_t  36864 | [92160) cs_t  36864 | [129024) dg_t 36864  -> 165888 total
__global__ void finalize_kernel(const float* __restrict__ ws, float* __restrict__ out) {
    const float* rs_ov = ws;
    const float* cs_ov = ws + 18432;
    const float* dg_ov = ws + 36864;
    const float* rs_t  = ws + 55296;
    const float* cs_t  = ws + 92160;
    const float* dg_t  = ws + 129024;
    float s_ov = 0.f, s_t = 0.f;
    for (int i = threadIdx.x; i < 18432; i += 256)
        s_ov += logf(rs_ov[i]) + logf(cs_ov[i]) - 2.f * dg_ov[i];
    for (int i = threadIdx.x; i < 36864; i += 256)
        s_t += logf(rs_t[i]) + logf(cs_t[i]) - 2.f * dg_t[i];
#pragma unroll
    for (int s = 1; s < 64; s <<= 1) {
        s_ov += __shfl_xor(s_ov, s);
        s_t  += __shfl_xor(s_t, s);
    }
    __shared__ float red[2][4];
    int w = threadIdx.x >> 6;
    if ((threadIdx.x & 63) == 0) { red[0][w] = s_ov; red[1][w] = s_t; }
    __syncthreads();
    if (threadIdx.x == 0) {
        float a = red[0][0] + red[0][1] + red[0][2] + red[0][3];
        float b = red[1][0] + red[1][1] + red[1][2] + red[1][3];
        out[0] = 0.5f * a / 18432.f + 0.05f * b / 36864.f;
    }
}

extern "C" void kernel_launch(void* const* d_in, const int* in_sizes, int n_in,
                              void* d_out, int out_size, void* d_ws, size_t ws_size,
                              hipStream_t stream) {
    const float* z1 = (const float*)d_in[0];
    const float* z2 = (const float*)d_in[1];
    float* out = (float*)d_out;
    float* ws  = (float*)d_ws;

    hipMemsetAsync(d_ws, 0, 165888 * sizeof(float), stream);

    dim3 blk(256, 1, 1);
    // overlap: M=2304 -> 18x18 tiles, 8 batches
    fused_gemm_lse<0><<<dim3(18, 18, 8), blk, 0, stream>>>(
        z1, z2, ws, ws + 18432, ws + 36864);
    // tile: M=576 -> ceil(576/128)=5 -> 5x5 tiles, 64 batches
    fused_gemm_lse<1><<<dim3(5, 5, 64), blk, 0, stream>>>(
        z1, z2, ws + 55296, ws + 92160, ws + 129024);
    finalize_kernel<<<1, 256, 0, stream>>>(ws, out);
}

// Round 2
// 381.671 us; speedup vs baseline: 1.6777x; 1.6777x over previous
//
#include <hip/hip_runtime.h>
#include <hip/hip_bf16.h>

typedef __attribute__((ext_vector_type(8))) short bf16x8_t;
typedef __attribute__((ext_vector_type(4))) float f32x4_t;
typedef __attribute__((ext_vector_type(8))) unsigned short u16x8_t;

__device__ inline unsigned short f2bf(float x) {
    union { float f; unsigned int u; } v; v.f = x;
    unsigned int r = v.u + 0x7FFFu + ((v.u >> 16) & 1u);
    return (unsigned short)(r >> 16);
}

__device__ inline void gl_lds16(const void* g, void* l) {
    __builtin_amdgcn_global_load_lds(
        (const __attribute__((address_space(1))) void*)g,
        (__attribute__((address_space(3))) void*)l, 16, 0, 0);
}

// ---------------- f32 -> bf16 convert (8 elems/thread/iter) ----------------
__global__ __launch_bounds__(256) void f32_to_bf16(
    const float* __restrict__ src, unsigned short* __restrict__ dst, int n8) {
    int stride = gridDim.x * blockDim.x;
    for (int i = blockIdx.x * blockDim.x + threadIdx.x; i < n8; i += stride) {
        const float4* p = (const float4*)(src + (size_t)i * 8);
        float4 a = p[0], b = p[1];
        u16x8_t v;
        v[0] = f2bf(a.x); v[1] = f2bf(a.y); v[2] = f2bf(a.z); v[3] = f2bf(a.w);
        v[4] = f2bf(b.x); v[5] = f2bf(b.y); v[6] = f2bf(b.z); v[7] = f2bf(b.w);
        *(u16x8_t*)(dst + (size_t)i * 8) = v;
    }
}

// ---------------- fast path: bf16 inputs, global_load_lds staging ----------
// MODE 0: overlap. M=2304, batch=v (0..7).
// MODE 1: tile.    M=576,  batch=bv (0..63).
template <int MODE>
__global__ __launch_bounds__(256) void fused_gemm_lse_bf16(
    const unsigned short* __restrict__ z1b, const unsigned short* __restrict__ z2b,
    float* __restrict__ rowsum, float* __restrict__ colsum,
    float* __restrict__ diag) {
    constexpr int M = (MODE == 0) ? 2304 : 576;
    constexpr float inv_tau = (MODE == 0) ? (1.0f / 0.07f) : (1.0f / 0.2f);

    const int tid  = threadIdx.x;
    const int lane = tid & 63;
    const int w    = tid >> 6;
    const int wM   = w >> 1;
    const int wN   = w & 1;
    const int lr   = lane & 15;
    const int lg   = lane >> 4;
    const int sub  = lane >> 3;   // row within 8-row chunk
    const int kb   = lane & 7;    // 16B slot within row
    const int brow = blockIdx.y, bcol = blockIdx.x, batch = blockIdx.z;

    __shared__ unsigned short lA[128][64];   // linear: required by global_load_lds
    __shared__ unsigned short lB[128][64];
    __shared__ int offA[128];
    __shared__ int offB[128];

    if (tid < 128) {
        int r = brow * 128 + tid;
        int off;
        if (MODE == 0) {
            int b = r / 288, rem = r % 288;
            int h = rem / 12, j = rem % 12;
            off = ((b * 8 + batch) * 576 + h * 24 + 12 + j) * 768;
        } else {
            off = ((r < M) ? (batch * 576 + r) : (batch * 576)) * 768;
        }
        offA[tid] = off;
    } else {
        int c = bcol * 128 + (tid - 128);
        int off;
        if (MODE == 0) {
            int b = c / 288, rem = c % 288;
            int h = rem / 12, j = rem % 12;
            off = ((b * 8 + ((batch + 1) & 7)) * 576 + h * 24 + j) * 768;
        } else {
            off = ((c < M) ? (batch * 576 + c) : (batch * 576)) * 768;
        }
        offB[tid - 128] = off;
    }
    __syncthreads();

    // per-lane global row offsets for the 4 A-chunks + 4 B-chunks this wave stages
    int oAc[4], oBc[4];
#pragma unroll
    for (int c = 0; c < 4; ++c) {
        oAc[c] = offA[w * 32 + c * 8 + sub];
        oBc[c] = offB[w * 32 + c * 8 + sub];
    }

    f32x4_t acc[4][4];
#pragma unroll
    for (int i = 0; i < 4; ++i)
#pragma unroll
        for (int j = 0; j < 4; ++j) acc[i][j] = (f32x4_t){0.f, 0.f, 0.f, 0.f};

    for (int kt = 0; kt < 12; ++kt) {
        const int k0 = kt * 64;
#pragma unroll
        for (int c = 0; c < 4; ++c) {
            gl_lds16(z1b + oAc[c] + k0 + kb * 8, &lA[w * 32 + c * 8][0]);
            gl_lds16(z2b + oBc[c] + k0 + kb * 8, &lB[w * 32 + c * 8][0]);
        }
        __syncthreads();
#pragma unroll
        for (int kk = 0; kk < 64; kk += 32) {
            bf16x8_t av[4], bv[4];
#pragma unroll
            for (int i = 0; i < 4; ++i) {
                av[i] = *(const bf16x8_t*)&lA[wM * 64 + i * 16 + lr][kk + lg * 8];
                bv[i] = *(const bf16x8_t*)&lB[wN * 64 + i * 16 + lr][kk + lg * 8];
            }
#pragma unroll
            for (int i = 0; i < 4; ++i)
#pragma unroll
                for (int j = 0; j < 4; ++j)
                    acc[i][j] = __builtin_amdgcn_mfma_f32_16x16x32_bf16(
                        av[i], bv[j], acc[i][j], 0, 0, 0);
        }
        __syncthreads();
    }

    const int rowbase = brow * 128 + wM * 64;
    const int colbase = bcol * 128 + wN * 64;
    float colacc[4] = {0.f, 0.f, 0.f, 0.f};
#pragma unroll
    for (int i = 0; i < 4; ++i) {
#pragma unroll
        for (int reg = 0; reg < 4; ++reg) {
            int row = rowbase + i * 16 + lg * 4 + reg;
            bool rv = row < M;
            float rp = 0.f;
#pragma unroll
            for (int j = 0; j < 4; ++j) {
                int col = colbase + j * 16 + lr;
                float L = acc[i][j][reg] * inv_tau;
                float e = (rv && (col < M)) ? __expf(L) : 0.f;
                rp += e;
                colacc[j] += e;
                if (rv && row == col) diag[batch * M + row] = L;
            }
#pragma unroll
            for (int s = 1; s < 16; s <<= 1) rp += __shfl_xor(rp, s);
            if (lr == 0 && rv) atomicAdd(&rowsum[batch * M + row], rp);
        }
    }
#pragma unroll
    for (int j = 0; j < 4; ++j) {
        float c = colacc[j];
        c += __shfl_xor(c, 16);
        c += __shfl_xor(c, 32);
        int col = colbase + j * 16 + lr;
        if (lg == 0 && col < M) atomicAdd(&colsum[batch * M + col], c);
    }
}

// ---------------- fallback path (R1, convert-in-flight) --------------------
template <int MODE>
__global__ __launch_bounds__(256) void fused_gemm_lse(
    const float* __restrict__ z1, const float* __restrict__ z2,
    float* __restrict__ rowsum, float* __restrict__ colsum,
    float* __restrict__ diag) {
    constexpr int M = (MODE == 0) ? 2304 : 576;
    constexpr float inv_tau = (MODE == 0) ? (1.0f / 0.07f) : (1.0f / 0.2f);

    const int tid  = threadIdx.x;
    const int lane = tid & 63;
    const int w    = tid >> 6;
    const int wM   = w >> 1;
    const int wN   = w & 1;
    const int lr   = lane & 15;
    const int lg   = lane >> 4;
    const int brow = blockIdx.y, bcol = blockIdx.x, batch = blockIdx.z;

    __shared__ unsigned short lA[128][72];
    __shared__ unsigned short lB[128][72];
    __shared__ int offA[128];
    __shared__ int offB[128];

    if (tid < 128) {
        int r = brow * 128 + tid;
        int off;
        if (MODE == 0) {
            int b = r / 288, rem = r % 288;
            int h = rem / 12, j = rem % 12;
            off = ((b * 8 + batch) * 576 + h * 24 + 12 + j) * 768;
        } else {
            off = (r < M) ? (batch * 576 + r) * 768 : -1;
        }
        offA[tid] = off;
    } else {
        int c = bcol * 128 + (tid - 128);
        int off;
        if (MODE == 0) {
            int b = c / 288, rem = c % 288;
            int h = rem / 12, j = rem % 12;
            off = ((b * 8 + ((batch + 1) & 7)) * 576 + h * 24 + j) * 768;
        } else {
            off = (c < M) ? (batch * 576 + c) * 768 : -1;
        }
        offB[tid - 128] = off;
    }
    __syncthreads();

    f32x4_t acc[4][4];
#pragma unroll
    for (int i = 0; i < 4; ++i)
#pragma unroll
        for (int j = 0; j < 4; ++j) acc[i][j] = (f32x4_t){0.f, 0.f, 0.f, 0.f};

    for (int kt = 0; kt < 12; ++kt) {
        const int k0 = kt * 64;
#pragma unroll
        for (int rr = 0; rr < 8; ++rr) {
            int f   = tid + (rr << 8);
            int row = f >> 4;
            int c4  = f & 15;
            int oA = offA[row], oB = offB[row];
            float4 va = make_float4(0.f, 0.f, 0.f, 0.f);
            float4 vb = make_float4(0.f, 0.f, 0.f, 0.f);
            if (oA >= 0) va = *(const float4*)(z1 + oA + k0 + (c4 << 2));
            if (oB >= 0) vb = *(const float4*)(z2 + oB + k0 + (c4 << 2));
            ushort4 sa, sb;
            sa.x = f2bf(va.x); sa.y = f2bf(va.y); sa.z = f2bf(va.z); sa.w = f2bf(va.w);
            sb.x = f2bf(vb.x); sb.y = f2bf(vb.y); sb.z = f2bf(vb.z); sb.w = f2bf(vb.w);
            *(ushort4*)&lA[row][c4 << 2] = sa;
            *(ushort4*)&lB[row][c4 << 2] = sb;
        }
        __syncthreads();
#pragma unroll
        for (int kk = 0; kk < 64; kk += 32) {
            bf16x8_t av[4], bv[4];
#pragma unroll
            for (int i = 0; i < 4; ++i) {
                av[i] = *(const bf16x8_t*)&lA[wM * 64 + i * 16 + lr][kk + lg * 8];
                bv[i] = *(const bf16x8_t*)&lB[wN * 64 + i * 16 + lr][kk + lg * 8];
            }
#pragma unroll
            for (int i = 0; i < 4; ++i)
#pragma unroll
                for (int j = 0; j < 4; ++j)
                    acc[i][j] = __builtin_amdgcn_mfma_f32_16x16x32_bf16(
                        av[i], bv[j], acc[i][j], 0, 0, 0);
        }
        __syncthreads();
    }

    const int rowbase = brow * 128 + wM * 64;
    const int colbase = bcol * 128 + wN * 64;
    float colacc[4] = {0.f, 0.f, 0.f, 0.f};
#pragma unroll
    for (int i = 0; i < 4; ++i) {
#pragma unroll
        for (int reg = 0; reg < 4; ++reg) {
            int row = rowbase + i * 16 + lg * 4 + reg;
            bool rv = row < M;
            float rp = 0.f;
#pragma unroll
            for (int j = 0; j < 4; ++j) {
                int col = colbase + j * 16 + lr;
                float L = acc[i][j][reg] * inv_tau;
                float e = (rv && (col < M)) ? __expf(L) : 0.f;
                rp += e;
                colacc[j] += e;
                if (rv && row == col) diag[batch * M + row] = L;
            }
#pragma unroll
            for (int s = 1; s < 16; s <<= 1) rp += __shfl_xor(rp, s);
            if (lr == 0 && rv) atomicAdd(&rowsum[batch * M + row], rp);
        }
    }
#pragma unroll
    for (int j = 0; j < 4; ++j) {
        float c = colacc[j];
        c += __shfl_xor(c, 16);
        c += __shfl_xor(c, 32);
        int col = colbase + j * 16 + lr;
        if (lg == 0 && col < M) atomicAdd(&colsum[batch * M + col], c);
    }
}

// ws float layout (accumulators first, both paths):
// [0) rs_ov 18432 | [18432) cs_ov 18432 | [36864) dg_ov 18432
// [55296) rs_t 36864 | [92160) cs_t 36864 | [129024) dg_t 36864 -> 165888
// fast path: bf16 z1 copy at byte 663552, bf16 z2 copy after it.
__global__ void finalize_kernel(const float* __restrict__ ws, float* __restrict__ out) {
    const float* rs_ov = ws;
    const float* cs_ov = ws + 18432;
    const float* dg_ov = ws + 36864;
    const float* rs_t  = ws + 55296;
    const float* cs_t  = ws + 92160;
    const float* dg_t  = ws + 129024;
    float s_ov = 0.f, s_t = 0.f;
    for (int i = threadIdx.x; i < 18432; i += 256)
        s_ov += logf(rs_ov[i]) + logf(cs_ov[i]) - 2.f * dg_ov[i];
    for (int i = threadIdx.x; i < 36864; i += 256)
        s_t += logf(rs_t[i]) + logf(cs_t[i]) - 2.f * dg_t[i];
#pragma unroll
    for (int s = 1; s < 64; s <<= 1) {
        s_ov += __shfl_xor(s_ov, s);
        s_t  += __shfl_xor(s_t, s);
    }
    __shared__ float red[2][4];
    int w = threadIdx.x >> 6;
    if ((threadIdx.x & 63) == 0) { red[0][w] = s_ov; red[1][w] = s_t; }
    __syncthreads();
    if (threadIdx.x == 0) {
        float a = red[0][0] + red[0][1] + red[0][2] + red[0][3];
        float b = red[1][0] + red[1][1] + red[1][2] + red[1][3];
        out[0] = 0.5f * a / 18432.f + 0.05f * b / 36864.f;
    }
}

extern "C" void kernel_launch(void* const* d_in, const int* in_sizes, int n_in,
                              void* d_out, int out_size, void* d_ws, size_t ws_size,
                              hipStream_t stream) {
    const float* z1 = (const float*)d_in[0];
    const float* z2 = (const float*)d_in[1];
    float* out = (float*)d_out;
    float* ws  = (float*)d_ws;

    const size_t N_ELEM  = (size_t)64 * 576 * 768;        // 28,311,552 per tensor
    const size_t ACC_B   = 165888 * sizeof(float);        // 663,552 B (16B aligned)
    const size_t BF_B    = N_ELEM * 2;
    const size_t NEED    = ACC_B + 2 * BF_B;

    hipMemsetAsync(d_ws, 0, ACC_B, stream);
    dim3 blk(256, 1, 1);

    if (ws_size >= NEED) {
        unsigned short* z1b = (unsigned short*)((char*)d_ws + ACC_B);
        unsigned short* z2b = z1b + N_ELEM;
        int n8 = (int)(N_ELEM / 8);
        f32_to_bf16<<<2048, blk, 0, stream>>>(z1, z1b, n8);
        f32_to_bf16<<<2048, blk, 0, stream>>>(z2, z2b, n8);
        fused_gemm_lse_bf16<0><<<dim3(18, 18, 8), blk, 0, stream>>>(
            z1b, z2b, ws, ws + 18432, ws + 36864);
        fused_gemm_lse_bf16<1><<<dim3(5, 5, 64), blk, 0, stream>>>(
            z1b, z2b, ws + 55296, ws + 92160, ws + 129024);
    } else {
        fused_gemm_lse<0><<<dim3(18, 18, 8), blk, 0, stream>>>(
            z1, z2, ws, ws + 18432, ws + 36864);
        fused_gemm_lse<1><<<dim3(5, 5, 64), blk, 0, stream>>>(
            z1, z2, ws + 55296, ws + 92160, ws + 129024);
    }
    finalize_kernel<<<1, 256, 0, stream>>>(ws, out);
}